// Round 3
// baseline (509.525 us; speedup 1.0000x reference)
//
#include <hip/hip_runtime.h>
#include <math.h>

#define TPC 225
#define NCLS 224
#define NHID 1024
#define BATCH 2048
#define CAP 256      // bucket capacity per class (mean ~9.1)
#define LSTRIDE 256  // logits ws row stride (floats)

// ---------------------------------------------------------------------------
// Kernel 1: bucket examples by class. Single block, LDS atomics.
// bucket[c*CAP + i] = row index
// ---------------------------------------------------------------------------
__global__ __launch_bounds__(256) void hs_bucket(const int* __restrict__ labels,
                                                 int* __restrict__ bucket,
                                                 int* __restrict__ cnt) {
    __shared__ int scnt[NCLS];
    const int t = threadIdx.x;
    for (int i = t; i < NCLS; i += 256) scnt[i] = 0;
    __syncthreads();
    for (int b = t; b < BATCH; b += 256) {
        int lab = labels[b];
        int c = lab / TPC;
        int pos = atomicAdd(&scnt[c], 1);
        bucket[c * CAP + pos] = b;
    }
    __syncthreads();
    for (int i = t; i < NCLS; i += 256) cnt[i] = scnt[i];
}

// ---------------------------------------------------------------------------
// K-loop core: R rows x 1 col/lane. W pipelined depth-4 (groups of 8 d),
// x pipelined depth-2. All W loads use imm offsets (u*WS*4 < 8191 bytes).
// ---------------------------------------------------------------------------
template <int R, int WS>
__device__ __forceinline__ void kloop(const float* __restrict__ wp,  // W + col
                                      const float* const xp[R],
                                      float acc[R]) {
    constexpr int NG = NHID / 8;  // 128 groups
    float wv[4][8];
    float4 xv[2][R][2];
#pragma unroll
    for (int r = 0; r < R; r++) acc[r] = 0.f;

    // prologue: W groups 0..3, x groups 0..1
#pragma unroll
    for (int b = 0; b < 4; b++)
#pragma unroll
        for (int u = 0; u < 8; u++) wv[b][u] = wp[(size_t)(b * 8 + u) * WS];
#pragma unroll
    for (int b = 0; b < 2; b++)
#pragma unroll
        for (int r = 0; r < R; r++) {
            xv[b][r][0] = *(const float4*)(xp[r] + b * 8);
            xv[b][r][1] = *(const float4*)(xp[r] + b * 8 + 4);
        }
    const float* wiss = wp + (size_t)32 * WS;
    const float* xiss[R];
#pragma unroll
    for (int r = 0; r < R; r++) xiss[r] = xp[r] + 16;

#pragma unroll 4
    for (int g = 0; g < NG - 4; ++g) {
        const int b = g & 3, xb = g & 1;
        // compute group g
#pragma unroll
        for (int u = 0; u < 8; u++) {
            const float w_u = wv[b][u];
#pragma unroll
            for (int r = 0; r < R; r++) {
                const float xval = ((const float*)&xv[xb][r][u >> 2])[u & 3];
                acc[r] = fmaf(xval, w_u, acc[r]);
            }
        }
        // issue W group g+4 (imm offsets), x group g+2
#pragma unroll
        for (int u = 0; u < 8; u++) wv[b][u] = wiss[(size_t)u * WS];
        wiss += 8 * WS;
#pragma unroll
        for (int r = 0; r < R; r++) {
            xv[xb][r][0] = *(const float4*)(xiss[r]);
            xv[xb][r][1] = *(const float4*)(xiss[r] + 4);
            xiss[r] += 8;
        }
    }
    // epilogue: groups NG-4..NG-1
#pragma unroll
    for (int g = NG - 4; g < NG; ++g) {
        const int b = g & 3, xb = g & 1;
#pragma unroll
        for (int u = 0; u < 8; u++) {
            const float w_u = wv[b][u];
#pragma unroll
            for (int r = 0; r < R; r++) {
                const float xval = ((const float*)&xv[xb][r][u >> 2])[u & 3];
                acc[r] = fmaf(xval, w_u, acc[r]);
            }
        }
        if (g + 2 < NG) {
#pragma unroll
            for (int r = 0; r < R; r++) {
                xv[xb][r][0] = *(const float4*)(xiss[r]);
                xv[xb][r][1] = *(const float4*)(xiss[r] + 4);
                xiss[r] += 8;
            }
        }
    }
}

// ---------------------------------------------------------------------------
// Kernel 2: top logits. 128 row-blocks x 4 col-tiles (56 cols, lane<56).
// W_top [NHID][NCLS] is L2-resident. tws[row*LSTRIDE + col] = logit.
// ---------------------------------------------------------------------------
__global__ __launch_bounds__(256, 2) void hs_tlogits(const float* __restrict__ x,
                                                     const float* __restrict__ W,
                                                     float* __restrict__ tws) {
    const int t = threadIdx.x;
    const int lane = t & 63;
    const int wave = t >> 6;
    const int r0 = (blockIdx.x >> 2) * 16 + wave * 4;
    const int tile = blockIdx.x & 3;
    const int col = tile * 56 + lane;
    const int colc = (lane < 56) ? col : (NCLS - 1);

    const float* xp[4];
#pragma unroll
    for (int r = 0; r < 4; r++) xp[r] = x + (size_t)(r0 + r) * NHID;
    float acc[4];
    kloop<4, NCLS>(W + colc, xp, acc);
    if (lane < 56) {
#pragma unroll
        for (int r = 0; r < 4; r++) tws[(size_t)(r0 + r) * LSTRIDE + col] = acc[r];
    }
}

// ---------------------------------------------------------------------------
// Kernel 3: bottom logits. Grid = 224 classes x 4 col-tiles (64 cols).
// Waves take 4-row strips of the class bucket. bws[row*LSTRIDE+col] = logit.
// ---------------------------------------------------------------------------
template <int R>
__device__ __forceinline__ void btile(const float* __restrict__ x,
                                      const float* __restrict__ Wcol,
                                      const int* __restrict__ bucket_c,
                                      const int base, const int col,
                                      float* __restrict__ bws) {
    int rowid[R];
    const float* xp[R];
#pragma unroll
    for (int r = 0; r < R; r++) {
        rowid[r] = __builtin_amdgcn_readfirstlane(bucket_c[base + r]);
        xp[r] = x + (size_t)rowid[r] * NHID;
    }
    float acc[R];
    kloop<R, TPC>(Wcol, xp, acc);
    if (col < TPC) {
#pragma unroll
        for (int r = 0; r < R; r++) bws[(size_t)rowid[r] * LSTRIDE + col] = acc[r];
    }
}

__global__ __launch_bounds__(256, 2) void hs_blogits(const float* __restrict__ x,
                                                     const float* __restrict__ Wb,
                                                     const int* __restrict__ bucket,
                                                     const int* __restrict__ cnt,
                                                     float* __restrict__ bws) {
    const int c = blockIdx.x >> 2;
    const int tile = blockIdx.x & 3;
    const int n = __builtin_amdgcn_readfirstlane(cnt[c]);
    if (n == 0) return;
    const int t = threadIdx.x;
    const int lane = t & 63;
    const int wave = t >> 6;
    const int col = tile * 64 + lane;
    const int colc = (col < TPC) ? col : (TPC - 1);
    const float* Wcol = Wb + (size_t)c * (NHID * TPC) + colc;
    const int* bucket_c = bucket + c * CAP;

    const int nstrips = (n + 3) >> 2;
    for (int s = wave; s < nstrips; s += 4) {
        const int base = s * 4;
        const int R = n - base < 4 ? n - base : 4;
        switch (R) {  // wave-uniform
            case 1: btile<1>(x, Wcol, bucket_c, base, col, bws); break;
            case 2: btile<2>(x, Wcol, bucket_c, base, col, bws); break;
            case 3: btile<3>(x, Wcol, bucket_c, base, col, bws); break;
            default: btile<4>(x, Wcol, bucket_c, base, col, bws); break;
        }
    }
}

// ---------------------------------------------------------------------------
// Kernel 4: finish. One wave per row: softmax over top (224) and bottom (225)
// logits, pick cls/word, out[row] = p_cls * p_word.
// ---------------------------------------------------------------------------
__global__ __launch_bounds__(256) void hs_finish(const float* __restrict__ tws,
                                                 const float* __restrict__ bws,
                                                 const int* __restrict__ labels,
                                                 const float* __restrict__ b_top,
                                                 const float* __restrict__ b_bot,
                                                 float* __restrict__ out) {
    const int lane = threadIdx.x & 63;
    const int wave = threadIdx.x >> 6;
    const int row = blockIdx.x * 4 + wave;
    const int label = labels[row];
    const int c = label / TPC;
    const int word = label - c * TPC;

    float p[2];  // p_cls, p_word
#pragma unroll
    for (int lvl = 0; lvl < 2; lvl++) {
        const int NS = lvl ? TPC : NCLS;
        const int pick = lvl ? word : c;
        const float* lws = lvl ? bws : tws;
        const float* bias = lvl ? (b_bot + c * TPC) : b_top;
        float lg[4];
#pragma unroll
        for (int j = 0; j < 4; j++) {
            int k = lane + 64 * j;
            lg[j] = (k < NS) ? lws[(size_t)row * LSTRIDE + k] + bias[k] : -INFINITY;
        }
        float m = fmaxf(fmaxf(lg[0], lg[1]), fmaxf(lg[2], lg[3]));
#pragma unroll
        for (int off = 32; off > 0; off >>= 1) m = fmaxf(m, __shfl_xor(m, off, 64));
        float s = 0.f, pp = 0.f;
#pragma unroll
        for (int j = 0; j < 4; j++) {
            int k = lane + 64 * j;
            float e = (k < NS) ? __expf(lg[j] - m) : 0.f;
            s += e;
            if (k == pick) pp = e;
        }
#pragma unroll
        for (int off = 32; off > 0; off >>= 1) {
            s += __shfl_xor(s, off, 64);
            pp += __shfl_xor(pp, off, 64);
        }
        p[lvl] = pp / s;
    }
    if (lane == 0) out[row] = p[0] * p[1];
}

// ---------------------------------------------------------------------------
extern "C" void kernel_launch(void* const* d_in, const int* in_sizes, int n_in,
                              void* d_out, int out_size, void* d_ws, size_t ws_size,
                              hipStream_t stream) {
    const float* inputs   = (const float*)d_in[0];
    const int*   labels   = (const int*)d_in[1];
    const float* W_top    = (const float*)d_in[2];
    const float* b_top    = (const float*)d_in[3];
    const float* W_bottom = (const float*)d_in[4];
    const float* b_bottom = (const float*)d_in[5];
    float* out = (float*)d_out;

    // ws layout: bucket[NCLS*CAP] | cnt[NCLS] | tws[BATCH*LSTRIDE] | bws[...]
    int* bucket = (int*)d_ws;
    int* cnt    = bucket + NCLS * CAP;
    float* tws  = (float*)(cnt + NCLS);
    float* bws  = tws + (size_t)BATCH * LSTRIDE;

    hs_bucket<<<1, 256, 0, stream>>>(labels, bucket, cnt);
    hs_tlogits<<<(BATCH / 16) * 4, 256, 0, stream>>>(inputs, W_top, tws);
    hs_blogits<<<NCLS * 4, 256, 0, stream>>>(inputs, W_bottom, bucket, cnt, bws);
    hs_finish<<<BATCH / 4, 256, 0, stream>>>(tws, bws, labels, b_top, b_bottom, out);
}

// Round 4
// 446.573 us; speedup vs baseline: 1.1410x; 1.1410x over previous
//
#include <hip/hip_runtime.h>
#include <math.h>

#define TPC 225
#define NCLS 224
#define NHID 1024
#define BATCH 2048
#define CAP 256      // bucket capacity per class (mean ~9.1)
#define LSTRIDE 256  // logits ws row stride (floats)

// ---------------------------------------------------------------------------
// Kernel 1: bucket examples by class. Single block, LDS atomics.
// ---------------------------------------------------------------------------
__global__ __launch_bounds__(256) void hs_bucket(const int* __restrict__ labels,
                                                 int* __restrict__ bucket,
                                                 int* __restrict__ cnt) {
    __shared__ int scnt[NCLS];
    const int t = threadIdx.x;
    for (int i = t; i < NCLS; i += 256) scnt[i] = 0;
    __syncthreads();
    for (int b = t; b < BATCH; b += 256) {
        int lab = labels[b];
        int c = lab / TPC;
        int pos = atomicAdd(&scnt[c], 1);
        bucket[c * CAP + pos] = b;
    }
    __syncthreads();
    for (int i = t; i < NCLS; i += 256) cnt[i] = scnt[i];
}

// ---------------------------------------------------------------------------
// Kernel 2: top logits. 256 blocks x 1024 threads. Block owns 8 rows.
// 16 waves = 2 row-groups (4 rows) x 8 d-eighths (128 d each).
// Lane owns k = lane + 64j. Partial sums reduced across d-eighths in LDS.
// ---------------------------------------------------------------------------
__global__ __launch_bounds__(1024, 4) void hs_tlogits(const float* __restrict__ x,
                                                      const float* __restrict__ W,
                                                      float* __restrict__ tws) {
    __shared__ float red[8 * 8 * 256];  // [wd][row][k] 64 KB
    const int t = threadIdx.x;
    const int lane = t & 63;
    const int wave = t >> 6;
    const int wr = wave & 1;   // row-group 0..1
    const int wd = wave >> 1;  // d-eighth 0..7
    const int r0 = blockIdx.x * 8;

    const float* pj[4];
#pragma unroll
    for (int j = 0; j < 4; j++) {
        int k = 64 * j + lane;
        pj[j] = W + (size_t)wd * 128 * NCLS + (k < NCLS ? k : NCLS - 1);
    }
    const float* xp[4];
#pragma unroll
    for (int rl = 0; rl < 4; rl++)
        xp[rl] = x + (size_t)(r0 + wr * 4 + rl) * NHID + wd * 128;

    float acc[4][4] = {};
    for (int dq = 0; dq < 32; ++dq) {
        float w[4][4];
#pragma unroll
        for (int di = 0; di < 4; di++)
#pragma unroll
            for (int j = 0; j < 4; j++) w[di][j] = pj[j][di * NCLS];
#pragma unroll
        for (int rl = 0; rl < 4; rl++) {
            float4 xq = *(const float4*)(xp[rl] + dq * 4);
#pragma unroll
            for (int di = 0; di < 4; di++) {
                float xv = ((const float*)&xq)[di];
#pragma unroll
                for (int j = 0; j < 4; j++)
                    acc[rl][j] = fmaf(xv, w[di][j], acc[rl][j]);
            }
        }
#pragma unroll
        for (int j = 0; j < 4; j++) pj[j] += 4 * NCLS;
    }
#pragma unroll
    for (int rl = 0; rl < 4; rl++)
#pragma unroll
        for (int j = 0; j < 4; j++)
            red[(wd * 8 + wr * 4 + rl) * 256 + 64 * j + lane] = acc[rl][j];
    __syncthreads();

    const int u = t & 255;
    for (int r = t >> 8; r < 8; r += 4) {
        if (u < NCLS) {
            float s = 0.f;
#pragma unroll
            for (int w8 = 0; w8 < 8; w8++) s += red[(w8 * 8 + r) * 256 + u];
            tws[(size_t)(r0 + r) * LSTRIDE + u] = s;
        }
    }
}

// ---------------------------------------------------------------------------
// Kernel 3: bottom logits. 224 blocks (one per class) x 1024 threads.
// 16 waves = 4 row-groups x 4 d-quarters (256 d each). Up to 16 rows per
// pass; W streamed from HBM exactly once per pass. x read from global
// (L2/L3-hot). Cross-wave d-reduction in 64 KB LDS.
// ---------------------------------------------------------------------------
template <int RW>
__device__ __forceinline__ void bpass(const float* __restrict__ x,
                                      const float* __restrict__ wb,
                                      const int* __restrict__ bucket_c,
                                      const int base, const int n,
                                      const int lane, const int wr, const int wd,
                                      float* __restrict__ red) {
    const float* xp[RW];
#pragma unroll
    for (int rl = 0; rl < RW; rl++) {
        int idx = base + wr * RW + rl;
        int row = bucket_c[idx < n ? idx : 0];  // pad rows alias entry 0
        xp[rl] = x + (size_t)row * NHID + wd * 256;
    }
    const float* pj[4];
#pragma unroll
    for (int j = 0; j < 4; j++) {
        int k = 64 * j + lane;
        pj[j] = wb + (k < TPC ? k : TPC - 1);
    }
    float acc[RW][4] = {};
    for (int dq = 0; dq < 64; ++dq) {
        float w[4][4];
#pragma unroll
        for (int di = 0; di < 4; di++)
#pragma unroll
            for (int j = 0; j < 4; j++) w[di][j] = pj[j][di * TPC];
#pragma unroll
        for (int rl = 0; rl < RW; rl++) {
            float4 xq = *(const float4*)(xp[rl] + dq * 4);
#pragma unroll
            for (int di = 0; di < 4; di++) {
                float xv = ((const float*)&xq)[di];
#pragma unroll
                for (int j = 0; j < 4; j++)
                    acc[rl][j] = fmaf(xv, w[di][j], acc[rl][j]);
            }
        }
#pragma unroll
        for (int j = 0; j < 4; j++) pj[j] += 4 * TPC;
    }
#pragma unroll
    for (int rl = 0; rl < RW; rl++)
#pragma unroll
        for (int j = 0; j < 4; j++)
            red[(wd * 16 + wr * RW + rl) * 256 + 64 * j + lane] = acc[rl][j];
}

__global__ __launch_bounds__(1024, 4) void hs_blogits(const float* __restrict__ x,
                                                      const float* __restrict__ Wb,
                                                      const int* __restrict__ bucket,
                                                      const int* __restrict__ cnt,
                                                      float* __restrict__ bws) {
    __shared__ float red[4 * 16 * 256];  // [wd][row][k] 64 KB
    const int c = blockIdx.x;
    const int n = cnt[c];
    if (n == 0) return;
    const int t = threadIdx.x;
    const int lane = t & 63;
    const int wave = t >> 6;
    const int wr = wave >> 2;  // row-group 0..3
    const int wd = wave & 3;   // d-quarter 0..3
    const float* wb = Wb + (size_t)c * (NHID * TPC) + (size_t)wd * 256 * TPC;
    const int* bucket_c = bucket + c * CAP;

    for (int base = 0; base < n; base += 16) {
        int m = n - base;
        if (m > 16) m = 16;
        const int RW = (m + 3) >> 2;
        if (base) __syncthreads();  // red reuse guard
        switch (RW) {  // block-uniform
            case 1: bpass<1>(x, wb, bucket_c, base, n, lane, wr, wd, red); break;
            case 2: bpass<2>(x, wb, bucket_c, base, n, lane, wr, wd, red); break;
            case 3: bpass<3>(x, wb, bucket_c, base, n, lane, wr, wd, red); break;
            default: bpass<4>(x, wb, bucket_c, base, n, lane, wr, wd, red); break;
        }
        __syncthreads();
        const int u = t & 255;
        for (int r = t >> 8; r < m; r += 4) {
            if (u < TPC) {
                float s = 0.f;
#pragma unroll
                for (int w4 = 0; w4 < 4; w4++) s += red[(w4 * 16 + r) * 256 + u];
                int row = bucket_c[base + r];
                bws[(size_t)row * LSTRIDE + u] = s;
            }
        }
    }
}

// ---------------------------------------------------------------------------
// Kernel 4: finish. One wave per row: softmax over top (224) and bottom (225)
// logits (bias added here), pick cls/word, out[row] = p_cls * p_word.
// ---------------------------------------------------------------------------
__global__ __launch_bounds__(256) void hs_finish(const float* __restrict__ tws,
                                                 const float* __restrict__ bws,
                                                 const int* __restrict__ labels,
                                                 const float* __restrict__ b_top,
                                                 const float* __restrict__ b_bot,
                                                 float* __restrict__ out) {
    const int lane = threadIdx.x & 63;
    const int wave = threadIdx.x >> 6;
    const int row = blockIdx.x * 4 + wave;
    const int label = labels[row];
    const int c = label / TPC;
    const int word = label - c * TPC;

    float p[2];
#pragma unroll
    for (int lvl = 0; lvl < 2; lvl++) {
        const int NS = lvl ? TPC : NCLS;
        const int pick = lvl ? word : c;
        const float* lws = lvl ? bws : tws;
        const float* bias = lvl ? (b_bot + c * TPC) : b_top;
        float lg[4];
#pragma unroll
        for (int j = 0; j < 4; j++) {
            int k = lane + 64 * j;
            lg[j] = (k < NS) ? lws[(size_t)row * LSTRIDE + k] + bias[k] : -INFINITY;
        }
        float m = fmaxf(fmaxf(lg[0], lg[1]), fmaxf(lg[2], lg[3]));
#pragma unroll
        for (int off = 32; off > 0; off >>= 1) m = fmaxf(m, __shfl_xor(m, off, 64));
        float s = 0.f, pp = 0.f;
#pragma unroll
        for (int j = 0; j < 4; j++) {
            int k = lane + 64 * j;
            float e = (k < NS) ? __expf(lg[j] - m) : 0.f;
            s += e;
            if (k == pick) pp = e;
        }
#pragma unroll
        for (int off = 32; off > 0; off >>= 1) {
            s += __shfl_xor(s, off, 64);
            pp += __shfl_xor(pp, off, 64);
        }
        p[lvl] = pp / s;
    }
    if (lane == 0) out[row] = p[0] * p[1];
}

// ---------------------------------------------------------------------------
extern "C" void kernel_launch(void* const* d_in, const int* in_sizes, int n_in,
                              void* d_out, int out_size, void* d_ws, size_t ws_size,
                              hipStream_t stream) {
    const float* inputs   = (const float*)d_in[0];
    const int*   labels   = (const int*)d_in[1];
    const float* W_top    = (const float*)d_in[2];
    const float* b_top    = (const float*)d_in[3];
    const float* W_bottom = (const float*)d_in[4];
    const float* b_bottom = (const float*)d_in[5];
    float* out = (float*)d_out;

    // ws layout: bucket[NCLS*CAP] | cnt[NCLS] | tws[BATCH*LSTRIDE] | bws[...]
    int* bucket = (int*)d_ws;
    int* cnt    = bucket + NCLS * CAP;
    float* tws  = (float*)(cnt + NCLS);
    float* bws  = tws + (size_t)BATCH * LSTRIDE;

    hs_bucket<<<1, 256, 0, stream>>>(labels, bucket, cnt);
    hs_tlogits<<<256, 1024, 0, stream>>>(inputs, W_top, tws);
    hs_blogits<<<NCLS, 1024, 0, stream>>>(inputs, W_bottom, bucket, cnt, bws);
    hs_finish<<<BATCH / 4, 256, 0, stream>>>(tws, bws, labels, b_top, b_bottom, out);
}